// Round 8
// baseline (108.175 us; speedup 1.0000x reference)
//
#include <hip/hip_runtime.h>

#define HH 256
#define LL 4096
#define STR 72          // LDS row stride in shorts (16B-aligned rows)

// ws byte offsets (~6.2 MB used, rewritten every call)
#define WS_H  0
#define WS_P  (2u*1024*1024)
#define WS_R  (4u*1024*1024)
#define WS_C1 (6u*1024*1024)
#define WS_C2 (6u*1024*1024 + 128u*1024)

typedef __attribute__((ext_vector_type(8))) short short8;   // 8 bf16 = MFMA A/B frag
typedef __attribute__((ext_vector_type(4))) float f32x4;    // MFMA C/D frag

static __device__ inline unsigned short f2bf(float x) {
    union { float f; unsigned u; } v; v.f = x;
    unsigned r = v.u + 0x7fffu + ((v.u >> 16) & 1u);   // RNE
    return (unsigned short)(r >> 16);
}
static __device__ inline float bf2f(unsigned short us) {
    union { unsigned u; float f; } v; v.u = ((unsigned)us) << 16; return v.f;
}

#define CMUL(or_, oi_, ar_, ai_, br_, bi_) do { \
    float _tr = fmaf((ar_), (br_), -(ai_) * (bi_)); \
    float _ti = fmaf((ar_), (bi_), (ai_) * (br_)); \
    (or_) = _tr; (oi_) = _ti; } while (0)

// ---------------- Precompute: one block per h ----------------
// h[0] += D (delta-tap fold). Rm stored (Re,Im)-INTERLEAVED along columns:
// Rm[k][2d] = Re r^k, Rm[k][2d+1] = -Im r^k, to match the paired Q layout.
__global__ __launch_bounds__(256) void s4_pre_kernel(
    const float* __restrict__ theta, const float* __restrict__ a,
    const float* __restrict__ b_p,   const float* __restrict__ c_p,
    const float* __restrict__ x0,    const float* __restrict__ Dp,
    unsigned short* __restrict__ Hm, unsigned short* __restrict__ Pm,
    unsigned short* __restrict__ Rm, float4* __restrict__ C1,
    float* __restrict__ C2)
{
    const int tid = threadIdx.x;
    const int h   = blockIdx.x;
    const int d   = tid & 31;
    const int kb  = tid >> 5;
    const float T = 1.0f / (LL - 1);
    __shared__ float h_s[64];

    const float lr = a[h * 32 + d];
    const float li = theta[h * 32 + d];
    const float Dh = Dp[h];
    float sn, cS;
    sincosf(li * T, &sn, &cS);
    const float er = expf(lr * T);
    const float Rr = er * cS, Ri = er * sn;      // r = exp(ls*T)
    const float den = lr * lr + li * li;
    const float t0r = ((Rr - 1.f) * lr + Ri * li) / den;
    const float t0i = (Ri * lr - (Rr - 1.f) * li) / den;
    const float qq  = b_p[h * 32 + d] * c_p[h * 32 + d];
    const float wre = 2.f * qq * t0r, wim = 2.f * qq * t0i;
    const float vv  = 4.f * T * c_p[h * 32 + d] * x0[h * 32 + d];

    float r2r, r2i, r4r, r4i, r8r, r8i, r16r, r16i, r32r, r32i;
    CMUL(r2r, r2i, Rr, Ri, Rr, Ri);
    CMUL(r4r, r4i, r2r, r2i, r2r, r2i);
    CMUL(r8r, r8i, r4r, r4i, r4r, r4i);
    CMUL(r16r, r16i, r8r, r8i, r8r, r8i);
    CMUL(r32r, r32i, r16r, r16i, r16r, r16i);

    unsigned short* HmB = Hm + h * 4096;
    unsigned short* PmB = Pm + h * 4096;
    unsigned short* RmB = Rm + h * 4096;

    {   // fill Rmat (interleaved), Pmat, reduce h_k
        float pr = 1.f, pi = 0.f;
        if (kb & 1) CMUL(pr, pi, pr, pi, r8r, r8i);
        if (kb & 2) CMUL(pr, pi, pr, pi, r16r, r16i);
        if (kb & 4) CMUL(pr, pi, pr, pi, r32r, r32i);
        #pragma unroll
        for (int k8 = 0; k8 < 8; ++k8) {
            const int k = (kb << 3) + k8;
            RmB[k * 64 + (d << 1)]     = f2bf(pr);
            RmB[k * 64 + (d << 1) + 1] = f2bf(-pi);
            PmB[d * 64 + (63 - k)]        = f2bf(pr);
            PmB[(32 + d) * 64 + (63 - k)] = f2bf(pi);
            float hk = fmaf(wre, pr, -wim * pi);     // Re(w * r^k)
            hk += __shfl_xor(hk, 1);
            hk += __shfl_xor(hk, 2);
            hk += __shfl_xor(hk, 4);
            hk += __shfl_xor(hk, 8);
            hk += __shfl_xor(hk, 16);
            if (d == 0) h_s[k] = hk + ((k == 0) ? Dh : 0.f);   // D fold
            CMUL(pr, pi, pr, pi, Rr, Ri);
        }
    }
    if (tid < 32) {
        float Ar, Ai, wrr, wri;
        CMUL(Ar, Ai, r32r, r32i, r32r, r32i);        // A = r^64
        CMUL(wrr, wri, wre, wim, Rr, Ri);            // w*r
        C1[h * 32 + d] = make_float4(Ar, Ai, wrr, wri);
        C2[h * 32 + d] = vv;
    }
    __syncthreads();

    {   // Toeplitz Hmat[t][tau] = h[t-tau]
        const int t  = tid >> 2;
        const int tb = (tid & 3) << 4;
        #pragma unroll
        for (int g = 0; g < 4; ++g) {
            const int tau0 = tb + (g << 2);
            unsigned short e[4];
            #pragma unroll
            for (int i = 0; i < 4; ++i) {
                const int dt = t - (tau0 + i);
                e[i] = (dt >= 0) ? f2bf(h_s[dt]) : (unsigned short)0;
            }
            uint2 pk;
            pk.x = (unsigned)e[0] | ((unsigned)e[1] << 16);
            pk.y = (unsigned)e[2] | ((unsigned)e[3] << 16);
            *(uint2*)&HmB[t * 64 + tau0] = pk;
        }
    }
}

// ---------------- Main: ONE WAVE per (b,h) tile; zero block barriers -------
// 512 blocks x 4 waves = 2048 waves, one tile each. Each wave owns a private
// 9 KB LDS region: stage -> mm1+mm2 -> intra-wave scan -> mm3 -> store.
__global__ __launch_bounds__(256, 2) void s4_main_kernel(
    const float* __restrict__ u,
    const unsigned short* __restrict__ Hm, const unsigned short* __restrict__ Pm,
    const unsigned short* __restrict__ Rm, const float4* __restrict__ C1,
    const float* __restrict__ C2, float* __restrict__ out)
{
    const int tid   = threadIdx.x;
    const int ln    = tid & 63;
    const int wslot = tid >> 6;
    const int wv    = (blockIdx.x << 2) + wslot;   // 0..2047
    const int hh    = wv >> 3;                     // 0..255
    const int b     = wv & 7;                      // 0..7
    const int rowi  = ln & 15;
    const int quad  = ln >> 4;
    const int d     = ln & 31;
    const int half  = ln >> 5;

    __shared__ __align__(16) short lds[4 * 64 * STR];
    short* Tt = lds + wslot * (64 * STR);          // this wave's tile

    // constants early (hide VMEM latency under staging)
    const float4 c1 = C1[hh * 32 + d];             // Ar, Ai, wr_r, wr_i
    const float vv  = C2[hh * 32 + d];

    // ---- stage u -> T[c][tau] bf16 ----
    const float* up = u + (((size_t)(b * HH + hh)) << 12);
    #pragma unroll
    for (int j0 = 0; j0 < 16; j0 += 4) {
        float4 vl[4];
        #pragma unroll
        for (int jj = 0; jj < 4; ++jj)
            vl[jj] = ((const float4*)up)[ln + ((j0 + jj) << 6)];
        #pragma unroll
        for (int jj = 0; jj < 4; ++jj) {
            const int v  = ln + ((j0 + jj) << 6);
            const int c  = v >> 4;
            const int t0 = (v & 15) << 2;
            uint2 pk;
            pk.x = (unsigned)f2bf(vl[jj].x) | ((unsigned)f2bf(vl[jj].y) << 16);
            pk.y = (unsigned)f2bf(vl[jj].z) | ((unsigned)f2bf(vl[jj].w) << 16);
            *(uint2*)&Tt[c * STR + t0] = pk;
        }
    }

    // ---- mm1 (Y = H x U) + mm2 (E = P x U): full 64x64 per wave ----
    const unsigned short* HmB = Hm + hh * 4096;
    const unsigned short* PmB = Pm + hh * 4096;
    const unsigned short* RmB = Rm + hh * 4096;
    f32x4 accY[4][4], accE[4][4];
    #pragma unroll
    for (int mt = 0; mt < 4; ++mt)
        #pragma unroll
        for (int nt = 0; nt < 4; ++nt) {
            accY[mt][nt] = (f32x4){0.f, 0.f, 0.f, 0.f};
            accE[mt][nt] = (f32x4){0.f, 0.f, 0.f, 0.f};
        }
    #pragma unroll
    for (int kh = 0; kh < 2; ++kh) {
        short8 bU[4];
        #pragma unroll
        for (int nt = 0; nt < 4; ++nt)
            bU[nt] = *(const short8*)&Tt[((nt << 4) + rowi) * STR + (kh << 5) + (quad << 3)];
        #pragma unroll
        for (int mt = 0; mt < 4; ++mt) {
            const int aoff = ((mt << 4) + rowi) * 64 + (kh << 5) + (quad << 3);
            const short8 aH = *(const short8*)&HmB[aoff];
            const short8 aP = *(const short8*)&PmB[aoff];
            #pragma unroll
            for (int nt = 0; nt < 4; ++nt) {
                accY[mt][nt] = __builtin_amdgcn_mfma_f32_16x16x32_bf16(aH, bU[nt], accY[mt][nt], 0, 0, 0);
                accE[mt][nt] = __builtin_amdgcn_mfma_f32_16x16x32_bf16(aP, bU[nt], accE[mt][nt], 0, 0, 0);
            }
        }
    }
    __builtin_amdgcn_wave_barrier();

    // ---- write E paired (Re,Im) over T: T[c][2d] = (Er,Ei) bf16 ----
    // accE rows: mt<2 -> Re of d=16mt+4quad+i ; mt+2 -> Im of same d
    #pragma unroll
    for (int mt = 0; mt < 2; ++mt)
        #pragma unroll
        for (int nt = 0; nt < 4; ++nt)
            #pragma unroll
            for (int i = 0; i < 4; ++i) {
                const int dd = (mt << 4) + (quad << 2) + i;
                const int c  = (nt << 4) + rowi;
                const unsigned pk = (unsigned)f2bf(accE[mt][nt][i])
                                  | ((unsigned)f2bf(accE[mt + 2][nt][i]) << 16);
                *(unsigned*)&Tt[c * STR + (dd << 1)] = pk;
            }
    __builtin_amdgcn_wave_barrier();

    // ---- intra-wave scan: lane (d, half) owns c in [32*half, 32*half+32) ----
    const float Ar = c1.x, Ai = c1.y, wrr = c1.z, wri = c1.w;
    float Sr = 0.f, Si = 0.f;
    #pragma unroll
    for (int i = 0; i < 32; ++i) {
        const unsigned ee = *(const unsigned*)&Tt[((half << 5) + i) * STR + (d << 1)];
        const float er_ = bf2f((unsigned short)(ee & 0xffffu));
        const float ei_ = bf2f((unsigned short)(ee >> 16));
        const float nr = fmaf(Ar, Sr, fmaf(-Ai, Si, er_));
        const float ni = fmaf(Ar, Si, fmaf(Ai, Sr, ei_));
        Sr = nr; Si = ni;
    }
    // half-0 segment sum -> half-1
    const float s0r = __shfl(Sr, d);
    const float s0i = __shfl(Si, d);
    // A^32 by 5 squarings
    float A5r = Ar, A5i = Ai;
    #pragma unroll
    for (int s = 0; s < 5; ++s) {
        const float nr = A5r * A5r - A5i * A5i;
        const float ni = 2.f * A5r * A5i;
        A5r = nr; A5i = ni;
    }
    float Gr = half ? vv * A5r : vv;
    float Gi = half ? vv * A5i : 0.f;
    float Zr = half ? s0r : 0.f;
    float Zi = half ? s0i : 0.f;
    #pragma unroll
    for (int i = 0; i < 32; ++i) {
        const int crow = ((half << 5) + i) * STR + (d << 1);
        const unsigned ee = *(const unsigned*)&Tt[crow];      // E (pre-overwrite)
        const float er_ = bf2f((unsigned short)(ee & 0xffffu));
        const float ei_ = bf2f((unsigned short)(ee >> 16));
        const float Qr = fmaf(wrr, Zr, fmaf(-wri, Zi, Gr));
        const float Qi = fmaf(wrr, Zi, fmaf(wri, Zr, Gi));
        const unsigned pk = (unsigned)f2bf(Qr) | ((unsigned)f2bf(Qi) << 16);
        *(unsigned*)&Tt[crow] = pk;                           // Q overwrites E
        const float nr = fmaf(Ar, Zr, fmaf(-Ai, Zi, er_));
        const float ni = fmaf(Ar, Zi, fmaf(Ai, Zr, ei_));
        Zr = nr; Zi = ni;
        float nGr, nGi;
        CMUL(nGr, nGi, Ar, Ai, Gr, Gi);
        Gr = nGr; Gi = nGi;
    }
    __builtin_amdgcn_wave_barrier();

    // ---- mm3: Y += R' x Q (R' interleaved to match paired Q) ----
    #pragma unroll
    for (int kh = 0; kh < 2; ++kh) {
        short8 bQ[4];
        #pragma unroll
        for (int nt = 0; nt < 4; ++nt)
            bQ[nt] = *(const short8*)&Tt[((nt << 4) + rowi) * STR + (kh << 5) + (quad << 3)];
        #pragma unroll
        for (int mt = 0; mt < 4; ++mt) {
            const short8 aR = *(const short8*)&RmB[((mt << 4) + rowi) * 64 + (kh << 5) + (quad << 3)];
            #pragma unroll
            for (int nt = 0; nt < 4; ++nt)
                accY[mt][nt] = __builtin_amdgcn_mfma_f32_16x16x32_bf16(aR, bQ[nt], accY[mt][nt], 0, 0, 0);
        }
    }

    // ---- stores: out[c*64 + k], c = 16nt+rowi, k = 16mt+4quad+i ----
    float* op = out + (((size_t)(b * HH + hh)) << 12);
    #pragma unroll
    for (int mt = 0; mt < 4; ++mt)
        #pragma unroll
        for (int nt = 0; nt < 4; ++nt) {
            const int c = (nt << 4) + rowi;
            const int k = (mt << 4) + (quad << 2);
            *(float4*)&op[c * 64 + k] = make_float4(accY[mt][nt][0], accY[mt][nt][1],
                                                    accY[mt][nt][2], accY[mt][nt][3]);
        }
}

extern "C" void kernel_launch(void* const* d_in, const int* in_sizes, int n_in,
                              void* d_out, int out_size, void* d_ws, size_t ws_size,
                              hipStream_t stream) {
    const float* u     = (const float*)d_in[0];
    const float* theta = (const float*)d_in[1];
    const float* a     = (const float*)d_in[2];
    const float* Dp    = (const float*)d_in[3];
    const float* b_p   = (const float*)d_in[4];
    const float* c_p   = (const float*)d_in[5];
    const float* x0    = (const float*)d_in[6];
    float* out = (float*)d_out;
    char* ws = (char*)d_ws;
    unsigned short* Hm = (unsigned short*)(ws + WS_H);
    unsigned short* Pm = (unsigned short*)(ws + WS_P);
    unsigned short* Rm = (unsigned short*)(ws + WS_R);
    float4*         C1 = (float4*)(ws + WS_C1);
    float*          C2 = (float*)(ws + WS_C2);

    hipLaunchKernelGGL(s4_pre_kernel, dim3(HH), dim3(256), 0, stream,
                       theta, a, b_p, c_p, x0, Dp, Hm, Pm, Rm, C1, C2);
    hipLaunchKernelGGL(s4_main_kernel, dim3(512), dim3(256), 0, stream,
                       u, Hm, Pm, Rm, C1, C2, out);
}